// Round 1
// baseline (104.290 us; speedup 1.0000x reference)
//
#include <hip/hip_runtime.h>
#include <math.h>

// Problem constants (from reference: POS_LEN=32, NUM_F=16, HIDDEN=256, T=32)
#define NUM_F   16
#define FIN     (8 * NUM_F)     // 128 fourier features
#define HIDDEN  256
#define TOUT    32
#define NOFF    63              // distinct offset values: -31..31
#define NPAIRS_TBL (NOFF * NOFF) // 3969

// Phase 1: compute the 63x63x32 lookup table.
// One block (256 threads) per (dr,dc) pair:
//   threads 0..127 compute fourier features into LDS,
//   all 256 threads compute one hidden unit each (dot-128 + SiLU),
//   threads 0..31 compute the output row (dot-256 + bias, * 1/sqrt(32)).
__global__ __launch_bounds__(HIDDEN) void gab_table_kernel(
    const float* __restrict__ freqs,
    const float* __restrict__ W1, const float* __restrict__ b1,
    const float* __restrict__ W2, const float* __restrict__ b2,
    float* __restrict__ table)
{
    const int pair = blockIdx.x;
    const float dr = (float)(pair / NOFF - (NOFF / 2));
    const float dc = (float)(pair % NOFF - (NOFF / 2));

    __shared__ float feats[FIN];
    __shared__ float h[HIDDEN];

    const int t = threadIdx.x;
    if (t < FIN) {
        const int g = t >> 4;       // feature group 0..7
        const int k = t & 15;       // frequency index
        const float f = freqs[k];
        float base;
        switch (g >> 1) {
            case 0:  base = dr;      break;  // a
            case 1:  base = dc;      break;  // b
            case 2:  base = dr + dc; break;  // p
            default: base = dr - dc; break;  // m
        }
        const float arg = base * f;
        feats[t] = (g & 1) ? cosf(arg) : sinf(arg);
    }
    __syncthreads();

    // hidden layer: h[t] = silu(W1[t,:] . feats + b1[t])
    {
        float acc = b1[t];
        const float* w = W1 + t * FIN;
        #pragma unroll
        for (int k = 0; k < FIN; ++k) acc = fmaf(w[k], feats[k], acc);
        h[t] = acc / (1.0f + expf(-acc));   // x * sigmoid(x)
    }
    __syncthreads();

    // output layer: out[o] = (W2[o,:] . h + b2[o]) * (1/sqrt(T))
    if (t < TOUT) {
        float acc = b2[t];
        const float* w = W2 + t * HIDDEN;
        #pragma unroll
        for (int k = 0; k < HIDDEN; ++k) acc = fmaf(w[k], h[k], acc);
        table[pair * TOUT + t] = acc * 0.17677669529663687f; // 1/sqrt(32)
    }
}

// Phase 2: gather. Each group of 8 threads handles one (i,j) pair:
// look up (dr,dc) -> table row (32 floats = 8 float4), coalesced float4 writes.
__global__ __launch_bounds__(256) void gab_gather_kernel(
    const float* __restrict__ dr, const float* __restrict__ dc,
    const float* __restrict__ table,
    float4* __restrict__ out, int npairs)
{
    const int total = npairs * 8;               // float4 elements of output
    const int stride = gridDim.x * blockDim.x;
    const float4* __restrict__ tbl4 = (const float4*)table;

    for (int idx = blockIdx.x * blockDim.x + threadIdx.x; idx < total; idx += stride) {
        const int p = idx >> 3;                 // pair index
        const int l = idx & 7;                  // float4 slot within the 32-float row
        const int ir = (int)rintf(dr[p]) + (NOFF / 2);
        const int ic = (int)rintf(dc[p]) + (NOFF / 2);
        out[idx] = tbl4[(ir * NOFF + ic) * (TOUT / 4) + l];
    }
}

extern "C" void kernel_launch(void* const* d_in, const int* in_sizes, int n_in,
                              void* d_out, int out_size, void* d_ws, size_t ws_size,
                              hipStream_t stream) {
    // inputs: 0 seq_len(int,1) 1 freqs(16) 2 W1(256*128) 3 b1(256)
    //         4 W2(32*256) 5 b2(32) 6 dr(S*S) 7 dc(S*S)
    const float* freqs = (const float*)d_in[1];
    const float* W1    = (const float*)d_in[2];
    const float* b1    = (const float*)d_in[3];
    const float* W2    = (const float*)d_in[4];
    const float* b2    = (const float*)d_in[5];
    const float* dr    = (const float*)d_in[6];
    const float* dc    = (const float*)d_in[7];
    float* out   = (float*)d_out;
    float* table = (float*)d_ws;                // 3969*32*4 = 508 KB scratch

    const int npairs = in_sizes[6];             // S*S = 1024*1024

    gab_table_kernel<<<NPAIRS_TBL, HIDDEN, 0, stream>>>(freqs, W1, b1, W2, b2, table);

    const int threads = 256;
    const int blocks  = 2048;                   // 8 blocks/CU, grid-stride the rest
    gab_gather_kernel<<<blocks, threads, 0, stream>>>(dr, dc, table, (float4*)out, npairs);
}

// Round 2
// 52.060 us; speedup vs baseline: 2.0033x; 2.0033x over previous
//
#include <hip/hip_runtime.h>
#include <math.h>

// Problem constants (reference: POS_LEN=32, NUM_F=16, HIDDEN=256, T=32)
#define NUM_F   16
#define FIN     (8 * NUM_F)      // 128 fourier features
#define HIDDEN  256
#define TOUT    32
#define NOFF    63               // distinct offset values: -31..31
#define NPAIRS_TBL (NOFF * NOFF) // 3969
#define PPB     8                // pairs per block
#define TBL_BLOCKS ((NPAIRS_TBL + PPB - 1) / PPB) // 497 -> round up to 512 grid

// Phase 1: 63x63x32 lookup table.
// 256 threads/block, 8 pairs/block. W1 row t lives in 32 float4 VGPRs
// (loaded once; the 4 consecutive float4 of a row share cache lines so W1
// is fetched exactly once per block). Per pair: feats -> LDS (broadcast
// reads), 128 FMA with 4 independent accumulators, SiLU, h -> LDS,
// output layer split 8-way per out unit + shfl/LDS reduce.
__global__ __launch_bounds__(256, 2) void gab_table_kernel(
    const float* __restrict__ freqs,
    const float* __restrict__ W1, const float* __restrict__ b1,
    const float* __restrict__ W2, const float* __restrict__ b2,
    float* __restrict__ table)
{
    __shared__ float feats[FIN];        // broadcast operand
    __shared__ float hbuf[HIDDEN];      // hidden activations
    __shared__ float part[4][33];       // cross-wave output partials (+1 pad)

    const int t = threadIdx.x;
    const int o = t & 31;               // output unit this thread contributes to
    const int c = t >> 5;               // k-chunk (0..7) of the dot-256

    // ---- one-time register staging -------------------------------------
    float4 w1r[32];                     // W1 row t (128 floats)
    {
        const float4* w1v = (const float4*)(W1 + t * FIN);
        #pragma unroll
        for (int k = 0; k < 32; ++k) w1r[k] = w1v[k];
    }
    float4 w2r[8];                      // W2[o][c*32 .. c*32+31]
    {
        const float4* w2v = (const float4*)(W2 + o * HIDDEN + c * 32);
        #pragma unroll
        for (int k = 0; k < 8; ++k) w2r[k] = w2v[k];
    }
    const float b1t = b1[t];
    const float b2o = b2[o];
    const float myfreq = (t < FIN) ? freqs[t & 15] : 0.0f;

    // ---- pair loop ------------------------------------------------------
    for (int pp = 0; pp < PPB; ++pp) {
        const int pair = blockIdx.x * PPB + pp;   // block-uniform
        if (pair >= NPAIRS_TBL) break;            // uniform break: safe w/ barriers
        const float dr = (float)(pair / NOFF - (NOFF / 2));
        const float dc = (float)(pair % NOFF - (NOFF / 2));

        if (t < FIN) {
            const int g = t >> 4;                 // feature group 0..7
            float base;
            switch (g >> 1) {
                case 0:  base = dr;      break;
                case 1:  base = dc;      break;
                case 2:  base = dr + dc; break;
                default: base = dr - dc; break;
            }
            const float arg = base * myfreq;
            feats[t] = (g & 1) ? cosf(arg) : sinf(arg);
        }
        __syncthreads();                          // feats write -> read

        // hidden unit t: dot-128 with 4 independent accumulators
        float a0 = 0.f, a1 = 0.f, a2 = 0.f, a3 = 0.f;
        const float4* f4 = (const float4*)feats;  // broadcast LDS reads
        #pragma unroll
        for (int k = 0; k < 32; k += 4) {
            float4 fa = f4[k + 0], fb = f4[k + 1], fc = f4[k + 2], fd = f4[k + 3];
            a0 = fmaf(w1r[k + 0].x, fa.x, a0); a1 = fmaf(w1r[k + 0].y, fa.y, a1);
            a2 = fmaf(w1r[k + 0].z, fa.z, a2); a3 = fmaf(w1r[k + 0].w, fa.w, a3);
            a0 = fmaf(w1r[k + 1].x, fb.x, a0); a1 = fmaf(w1r[k + 1].y, fb.y, a1);
            a2 = fmaf(w1r[k + 1].z, fb.z, a2); a3 = fmaf(w1r[k + 1].w, fb.w, a3);
            a0 = fmaf(w1r[k + 2].x, fc.x, a0); a1 = fmaf(w1r[k + 2].y, fc.y, a1);
            a2 = fmaf(w1r[k + 2].z, fc.z, a2); a3 = fmaf(w1r[k + 2].w, fc.w, a3);
            a0 = fmaf(w1r[k + 3].x, fd.x, a0); a1 = fmaf(w1r[k + 3].y, fd.y, a1);
            a2 = fmaf(w1r[k + 3].z, fd.z, a2); a3 = fmaf(w1r[k + 3].w, fd.w, a3);
        }
        const float pre = (a0 + a1) + (a2 + a3) + b1t;
        hbuf[t] = pre / (1.0f + expf(-pre));      // SiLU
        __syncthreads();                          // hbuf write -> read

        // output layer: thread (o,c) does 32 of the dot-256
        float s0 = 0.f, s1 = 0.f, s2 = 0.f, s3 = 0.f;
        const float4* h4 = (const float4*)(hbuf + c * 32);
        #pragma unroll
        for (int k = 0; k < 8; k += 2) {
            float4 ha = h4[k], hb = h4[k + 1];
            s0 = fmaf(w2r[k].x,     ha.x, s0); s1 = fmaf(w2r[k].y,     ha.y, s1);
            s2 = fmaf(w2r[k].z,     ha.z, s2); s3 = fmaf(w2r[k].w,     ha.w, s3);
            s0 = fmaf(w2r[k + 1].x, hb.x, s0); s1 = fmaf(w2r[k + 1].y, hb.y, s1);
            s2 = fmaf(w2r[k + 1].z, hb.z, s2); s3 = fmaf(w2r[k + 1].w, hb.w, s3);
        }
        float s = (s0 + s1) + (s2 + s3);
        s += __shfl_xor(s, 32);                   // merge the wave's two c-chunks
        if ((t & 63) < 32) part[t >> 6][o] = s;   // one row per wave
        __syncthreads();                          // part write -> read

        if (t < TOUT) {
            const float r = part[0][t] + part[1][t] + part[2][t] + part[3][t] + b2o;
            table[pair * TOUT + t] = r * 0.17677669529663687f; // * 1/sqrt(32)
        }
    }
}

// Phase 2: gather. dr/dc are derived exactly from the flat index
// (dr[i,j] = i/32 - j/32, dc[i,j] = i%32 - j%32 for S=1024, POS_LEN=32),
// so the only HBM traffic is the 128 MiB coalesced float4 output stream;
// the 508 KB table stays L2-resident.
__global__ __launch_bounds__(256) void gab_gather_kernel(
    const float* __restrict__ table,
    float4* __restrict__ out, int npairs)
{
    const int total = npairs * 8;                 // float4 elements of output
    const int stride = gridDim.x * blockDim.x;
    const float4* __restrict__ tbl4 = (const float4*)table;

    for (int idx = blockIdx.x * blockDim.x + threadIdx.x; idx < total; idx += stride) {
        const int p = idx >> 3;                   // pair index = i*1024 + j
        const int l = idx & 7;                    // float4 slot within the row
        const int i = p >> 10;
        const int j = p & 1023;
        const int ir = (i >> 5) - (j >> 5) + (NOFF / 2);
        const int ic = (i & 31) - (j & 31) + (NOFF / 2);
        out[idx] = tbl4[(ir * NOFF + ic) * (TOUT / 4) + l];
    }
}

extern "C" void kernel_launch(void* const* d_in, const int* in_sizes, int n_in,
                              void* d_out, int out_size, void* d_ws, size_t ws_size,
                              hipStream_t stream) {
    // inputs: 0 seq_len(int,1) 1 freqs(16) 2 W1(256*128) 3 b1(256)
    //         4 W2(32*256) 5 b2(32) 6 dr(S*S) 7 dc(S*S)
    const float* freqs = (const float*)d_in[1];
    const float* W1    = (const float*)d_in[2];
    const float* b1    = (const float*)d_in[3];
    const float* W2    = (const float*)d_in[4];
    const float* b2    = (const float*)d_in[5];
    float* out   = (float*)d_out;
    float* table = (float*)d_ws;                  // 3969*32*4 = 508 KB scratch

    const int npairs = in_sizes[6];               // S*S = 1024*1024

    gab_table_kernel<<<512, 256, 0, stream>>>(freqs, W1, b1, W2, b2, table);

    gab_gather_kernel<<<2048, 256, 0, stream>>>(table, (float4*)out, npairs);
}